// Round 1
// 1398.243 us; speedup vs baseline: 1.0142x; 1.0142x over previous
//
#include <hip/hip_runtime.h>

#define NTOK 64
#define DIM 256
#define NH 8
#define BWIN 4096
#define TOPK 51

typedef _Float16 f16;
typedef _Float16 f16x8 __attribute__((ext_vector_type(8)));
typedef _Float16 f16x4 __attribute__((ext_vector_type(4)));
typedef float f32x4 __attribute__((ext_vector_type(4)));

#define MFMA32(a, b, c) __builtin_amdgcn_mfma_f32_16x16x32_f16((a), (b), (c), 0, 0, 0)
#define MFMA16(a, b, c) __builtin_amdgcn_mfma_f32_16x16x16f16((a), (b), (c), 0, 0, 0)

// ---------------- prep: transpose weights to fp16, gather bias table (transposed) ----------------
__global__ void prep_kernel(const float* __restrict__ Wqkv, const float* __restrict__ Wproj,
                            const float* __restrict__ bias_table, const int* __restrict__ rel_index,
                            f16* __restrict__ Wqt, f16* __restrict__ Wpt, float* __restrict__ biasp) {
    int tid = blockIdx.x * blockDim.x + threadIdx.x;
    const int nq = 768 * 256, np = 256 * 256, nb = NH * NTOK * NTOK;
    for (int i = tid; i < nq + np + nb; i += gridDim.x * blockDim.x) {
        if (i < nq) {
            int o = i >> 8, d = i & 255;
            Wqt[i] = (f16)Wqkv[d * 768 + o];
        } else if (i < nq + np) {
            int j = i - nq;
            int o = j >> 8, d = j & 255;
            Wpt[j] = (f16)Wproj[d * 256 + o];
        } else {
            int j = i - nq - np;
            int h = j >> 12;          // j / 4096
            int nm = j & 4095;        // n*64 + m
            int n = nm >> 6, m = nm & 63;
            // transposed: biasp[h][m(key)][n(query)] for the swapped-S (K·Q^T) read pattern
            biasp[(h << 12) + (m << 6) + n] = bias_table[rel_index[nm] * NH + h];
        }
    }
}

// ---------------- fused per-window kernel: 1 block (512 thr, 8 waves) per window ----------------
// Wave w handles head h=w end-to-end with zero barriers inside the head phase.
__global__ __launch_bounds__(512, 4)
void swin_kernel(const float* __restrict__ x, const float* __restrict__ var,
                 const float* __restrict__ b_qkv, const float* __restrict__ b_proj,
                 const f16* __restrict__ Wqt, const f16* __restrict__ Wpt,
                 const float* __restrict__ biasp, float* __restrict__ out) {
    __shared__ __align__(16) struct {
        f16 xv[64][264];                    // var(hi) in phase 1, x in phase 2   33792 B
        union {
            f16 oh[NH][64][40];             // per-head attn output              40960 B
            f16 lo[64][264];                // var low part (phase 1)            33792 B
            float vs[64][65];               // var_self scores                   16640 B
        } u;
        unsigned char modT[64][65];         // [key][query] topk flag             4160 B
    } sm;                                   // total 78912 B -> 2 blocks/CU

    const int tid = threadIdx.x;
    const int lane = tid & 63;
    const int w = tid >> 6;                 // wave 0..7 (= head id in phase 2)
    const int lc = lane & 15;
    const int lq = lane >> 4;
    const int bwin = blockIdx.x;

    const float* varp = var + (size_t)bwin * NTOK * DIM;
    const float* xp = x + (size_t)bwin * NTOK * DIM;
    float* outp = out + (size_t)bwin * NTOK * DIM;

    // ---- phase 0: issue all global loads early; split var into fp16 hi + lo ----
    float4 v4[8], x4[8];
    #pragma unroll
    for (int it = 0; it < 8; ++it) v4[it] = ((const float4*)varp)[it * 512 + tid];
    #pragma unroll
    for (int it = 0; it < 8; ++it) x4[it] = ((const float4*)xp)[it * 512 + tid];
    #pragma unroll
    for (int it = 0; it < 8; ++it) {
        int i = it * 512 + tid;
        int r = i >> 6, c4 = i & 63;
        float4 vv = v4[it];
        f16 h0 = (f16)vv.x, h1 = (f16)vv.y, h2 = (f16)vv.z, h3 = (f16)vv.w;
        f16x4 hv = {h0, h1, h2, h3};
        f16x4 lv = {(f16)(vv.x - (float)h0), (f16)(vv.y - (float)h1),
                    (f16)(vv.z - (float)h2), (f16)(vv.w - (float)h3)};
        *(f16x4*)&sm.xv[r][c4 * 4] = hv;
        *(f16x4*)&sm.u.lo[r][c4 * 4] = lv;
    }
    __syncthreads();

    // ---- phase 1: var_self = var @ var^T (split-fp16, ~fp32 accuracy), 2 tiles/wave ----
    {
        const int rs = w >> 1;
        f32x4 vacc[2];
        vacc[0] = (f32x4){0.f, 0.f, 0.f, 0.f};
        vacc[1] = (f32x4){0.f, 0.f, 0.f, 0.f};
        #pragma unroll
        for (int ks = 0; ks < 8; ++ks) {
            int k0 = ks * 32 + lq * 8;
            f16x8 ahi = *(const f16x8*)&sm.xv[rs * 16 + lc][k0];
            f16x8 alo = *(const f16x8*)&sm.u.lo[rs * 16 + lc][k0];
            #pragma unroll
            for (int m = 0; m < 2; ++m) {
                int mt = (w & 1) * 2 + m;
                f16x8 bhi = *(const f16x8*)&sm.xv[mt * 16 + lc][k0];
                f16x8 blo = *(const f16x8*)&sm.u.lo[mt * 16 + lc][k0];
                vacc[m] = MFMA32(ahi, bhi, vacc[m]);
                vacc[m] = MFMA32(ahi, blo, vacc[m]);
                vacc[m] = MFMA32(alo, bhi, vacc[m]);
            }
        }
        __syncthreads();   // all lo/var-hi reads done before vs (aliased) written / xv overwritten
        #pragma unroll
        for (int m = 0; m < 2; ++m) {
            int mt = (w & 1) * 2 + m;
            #pragma unroll
            for (int r = 0; r < 4; ++r)
                sm.u.vs[rs * 16 + lq * 4 + r][mt * 16 + lc] = vacc[m][r];
        }
    }
    // store x (fp16) into xv (var-hi dead)
    #pragma unroll
    for (int it = 0; it < 8; ++it) {
        int i = it * 512 + tid;
        int r = i >> 6, c4 = i & 63;
        float4 vv = x4[it];
        f16x4 hv = {(f16)vv.x, (f16)vv.y, (f16)vv.z, (f16)vv.w};
        *(f16x4*)&sm.xv[r][c4 * 4] = hv;
    }
    __syncthreads();

    // ---- topk rank count: thread (row=tid>>3, part=tid&7) handles 8 cols ----
    {
        int n = tid >> 3, part = tid & 7;
        float vm[8];
        int cnt[8];
        #pragma unroll
        for (int i = 0; i < 8; ++i) { vm[i] = sm.u.vs[n][part * 8 + i]; cnt[i] = 0; }
        for (int j = 0; j < 64; ++j) {
            float vj = sm.u.vs[n][j];
            #pragma unroll
            for (int i = 0; i < 8; ++i) {
                int mi = part * 8 + i;
                cnt[i] += (int)((vj > vm[i]) | ((vj == vm[i]) & (j < mi)));
            }
        }
        #pragma unroll
        for (int i = 0; i < 8; ++i)
            sm.modT[part * 8 + i][n] = (cnt[i] < TOPK) ? 1 : 0;   // [key][query]
    }
    __syncthreads();

    // ================= phase 2: wave w == head h, fully register-resident =================
    const int h = w;
    const float scale = 0.17677669529663687f;   // 32^-0.5
    const f16* Wq = Wqt + (size_t)(h * 32) * 256;
    const f16* Wk = Wqt + (size_t)(256 + h * 32) * 256;
    const f16* Wv = Wqt + (size_t)(512 + h * 32) * 256;

    float bqr[2][4], bkr[2][4], bvl[2];
    #pragma unroll
    for (int ot = 0; ot < 2; ++ot)
        #pragma unroll
        for (int r = 0; r < 4; ++r) {
            bqr[ot][r] = b_qkv[h * 32 + ot * 16 + lq * 4 + r];
            bkr[ot][r] = b_qkv[256 + h * 32 + ot * 16 + lq * 4 + r];
        }
    #pragma unroll
    for (int cd = 0; cd < 2; ++cd) bvl[cd] = b_qkv[512 + h * 32 + cd * 16 + lc];

    // q^T = Wq·x^T, k^T = Wk·x^T (C-layout == transposed-operand frag), v = x·Wv^T
    f16x4 qop[2][4], kop[2][4], vop[2][4];   // [ot][token-tile] / [d-tile][token-tile]
    {
        f32x4 acc[2][4];
        // ---- q ----
        #pragma unroll
        for (int a = 0; a < 2; ++a)
            #pragma unroll
            for (int b = 0; b < 4; ++b) acc[a][b] = (f32x4){0.f, 0.f, 0.f, 0.f};
        #pragma unroll
        for (int ks = 0; ks < 8; ++ks) {
            int k0 = ks * 32 + lq * 8;
            f16x8 xf[4], wf[2];
            #pragma unroll
            for (int tt = 0; tt < 4; ++tt) xf[tt] = *(const f16x8*)&sm.xv[tt * 16 + lc][k0];
            #pragma unroll
            for (int ot = 0; ot < 2; ++ot) wf[ot] = *(const f16x8*)&Wq[(size_t)(ot * 16 + lc) * 256 + k0];
            #pragma unroll
            for (int ot = 0; ot < 2; ++ot)
                #pragma unroll
                for (int tt = 0; tt < 4; ++tt)
                    acc[ot][tt] = MFMA32(wf[ot], xf[tt], acc[ot][tt]);   // D[outdim][token]
        }
        #pragma unroll
        for (int ot = 0; ot < 2; ++ot)
            #pragma unroll
            for (int tt = 0; tt < 4; ++tt)
                #pragma unroll
                for (int r = 0; r < 4; ++r)
                    qop[ot][tt][r] = (f16)((acc[ot][tt][r] + bqr[ot][r]) * scale);
        // ---- k ----
        #pragma unroll
        for (int a = 0; a < 2; ++a)
            #pragma unroll
            for (int b = 0; b < 4; ++b) acc[a][b] = (f32x4){0.f, 0.f, 0.f, 0.f};
        #pragma unroll
        for (int ks = 0; ks < 8; ++ks) {
            int k0 = ks * 32 + lq * 8;
            f16x8 xf[4], wf[2];
            #pragma unroll
            for (int tt = 0; tt < 4; ++tt) xf[tt] = *(const f16x8*)&sm.xv[tt * 16 + lc][k0];
            #pragma unroll
            for (int ot = 0; ot < 2; ++ot) wf[ot] = *(const f16x8*)&Wk[(size_t)(ot * 16 + lc) * 256 + k0];
            #pragma unroll
            for (int ot = 0; ot < 2; ++ot)
                #pragma unroll
                for (int tt = 0; tt < 4; ++tt)
                    acc[ot][tt] = MFMA32(wf[ot], xf[tt], acc[ot][tt]);
        }
        #pragma unroll
        for (int ot = 0; ot < 2; ++ot)
            #pragma unroll
            for (int tt = 0; tt < 4; ++tt)
                #pragma unroll
                for (int r = 0; r < 4; ++r)
                    kop[ot][tt][r] = (f16)(acc[ot][tt][r] + bkr[ot][r]);
        // ---- v (untransposed: D[token][d] -> operand is V^T) ----
        #pragma unroll
        for (int a = 0; a < 2; ++a)
            #pragma unroll
            for (int b = 0; b < 4; ++b) acc[a][b] = (f32x4){0.f, 0.f, 0.f, 0.f};
        #pragma unroll
        for (int ks = 0; ks < 8; ++ks) {
            int k0 = ks * 32 + lq * 8;
            f16x8 xf[4], wf[2];
            #pragma unroll
            for (int tt = 0; tt < 4; ++tt) xf[tt] = *(const f16x8*)&sm.xv[tt * 16 + lc][k0];
            #pragma unroll
            for (int cd = 0; cd < 2; ++cd) wf[cd] = *(const f16x8*)&Wv[(size_t)(cd * 16 + lc) * 256 + k0];
            #pragma unroll
            for (int cd = 0; cd < 2; ++cd)
                #pragma unroll
                for (int tt = 0; tt < 4; ++tt)
                    acc[cd][tt] = MFMA32(xf[tt], wf[cd], acc[cd][tt]);   // D[token][d]
        }
        #pragma unroll
        for (int cd = 0; cd < 2; ++cd)
            #pragma unroll
            for (int tt = 0; tt < 4; ++tt)
                #pragma unroll
                for (int r = 0; r < 4; ++r)
                    vop[cd][tt][r] = (f16)(acc[cd][tt][r] + bvl[cd]);
    }

    // ---- dots (S^T = K·Q^T, K=16 chained MFMA) + softmax per query-tile, all in-register ----
    f16x4 pop[4][4];   // P operand frags [query-tile][key-chunk]
    float ls[4];
    const float* bt = biasp + h * 4096;   // [key][query]
    #pragma unroll
    for (int ci = 0; ci < 4; ++ci) {
        f32x4 st[4];   // S^T tiles: row=key (quad), col=query (lane)
        #pragma unroll
        for (int rj = 0; rj < 4; ++rj) {
            f32x4 z = (f32x4){0.f, 0.f, 0.f, 0.f};
            z = MFMA16(kop[0][rj], qop[0][ci], z);
            st[rj] = MFMA16(kop[1][rj], qop[1][ci], z);
        }
        float mx = -1e30f;
        #pragma unroll
        for (int rj = 0; rj < 4; ++rj)
            #pragma unroll
            for (int r = 0; r < 4; ++r) {
                int j = rj * 16 + lq * 4 + r;
                float modv = sm.modT[j][ci * 16 + lc] ? 1.0f : 1.2f;
                float t = st[rj][r] * modv + bt[j * 64 + ci * 16 + lc];
                st[rj][r] = t;
                mx = fmaxf(mx, t);
            }
        mx = fmaxf(mx, __shfl_xor(mx, 16));   // reduce over key rows = quads
        mx = fmaxf(mx, __shfl_xor(mx, 32));
        float s = 0.f;
        #pragma unroll
        for (int rj = 0; rj < 4; ++rj)
            #pragma unroll
            for (int r = 0; r < 4; ++r) {
                float e = __expf(st[rj][r] - mx);
                st[rj][r] = e;
                s += e;
            }
        s += __shfl_xor(s, 16);
        s += __shfl_xor(s, 32);
        ls[ci] = s;
        #pragma unroll
        for (int rj = 0; rj < 4; ++rj)
            #pragma unroll
            for (int r = 0; r < 4; ++r)
                pop[ci][rj][r] = (f16)st[rj][r];
    }

    // ---- PV: out = P @ V (K=16 chained), normalize, write oh ----
    {
        f32x4 oacc[4][2];
        #pragma unroll
        for (int ti = 0; ti < 4; ++ti)
            #pragma unroll
            for (int cd = 0; cd < 2; ++cd) oacc[ti][cd] = (f32x4){0.f, 0.f, 0.f, 0.f};
        #pragma unroll
        for (int kc = 0; kc < 4; ++kc)
            #pragma unroll
            for (int ti = 0; ti < 4; ++ti)
                #pragma unroll
                for (int cd = 0; cd < 2; ++cd)
                    oacc[ti][cd] = MFMA16(pop[ti][kc], vop[cd][kc], oacc[ti][cd]);   // D[token][d]
        float inv[4];
        #pragma unroll
        for (int ci = 0; ci < 4; ++ci) inv[ci] = 1.0f / ls[ci];
        #pragma unroll
        for (int ti = 0; ti < 4; ++ti)
            #pragma unroll
            for (int r = 0; r < 4; ++r) {
                float rl = __shfl(inv[ti], lq * 4 + r);   // lsum lives at lane (query&15)
                #pragma unroll
                for (int cd = 0; cd < 2; ++cd)
                    sm.u.oh[w][ti * 16 + lq * 4 + r][cd * 16 + lc] = (f16)(oacc[ti][cd][r] * rl);
            }
    }
    __syncthreads();

    // ---- proj: final = concat(oh) @ Wproj + b_proj ; wave owns 32-col strip ----
    {
        f32x4 facc[4][2];
        #pragma unroll
        for (int rt = 0; rt < 4; ++rt)
            #pragma unroll
            for (int ct = 0; ct < 2; ++ct) facc[rt][ct] = (f32x4){0.f, 0.f, 0.f, 0.f};
        #pragma unroll
        for (int hh = 0; hh < NH; ++hh) {
            f16x8 pf[4], wfp[2];
            #pragma unroll
            for (int rt = 0; rt < 4; ++rt)
                pf[rt] = *(const f16x8*)&sm.u.oh[hh][rt * 16 + lc][lq * 8];
            #pragma unroll
            for (int ct = 0; ct < 2; ++ct)
                wfp[ct] = *(const f16x8*)&Wpt[(size_t)(w * 32 + ct * 16 + lc) * 256 + hh * 32 + lq * 8];
            #pragma unroll
            for (int rt = 0; rt < 4; ++rt)
                #pragma unroll
                for (int ct = 0; ct < 2; ++ct)
                    facc[rt][ct] = MFMA32(pf[rt], wfp[ct], facc[rt][ct]);   // D[token][outcol]
        }
        #pragma unroll
        for (int ct = 0; ct < 2; ++ct) {
            int col = w * 32 + ct * 16 + lc;
            float bp = b_proj[col];
            #pragma unroll
            for (int rt = 0; rt < 4; ++rt)
                #pragma unroll
                for (int r = 0; r < 4; ++r)
                    outp[(rt * 16 + lq * 4 + r) * 256 + col] = facc[rt][ct][r] + bp;
        }
    }
}

extern "C" void kernel_launch(void* const* d_in, const int* in_sizes, int n_in,
                              void* d_out, int out_size, void* d_ws, size_t ws_size,
                              hipStream_t stream) {
    const float* x          = (const float*)d_in[0];
    const float* var        = (const float*)d_in[1];
    const float* W_qkv      = (const float*)d_in[2];
    const float* b_qkv      = (const float*)d_in[3];
    const float* W_proj     = (const float*)d_in[4];
    const float* b_proj     = (const float*)d_in[5];
    const float* bias_table = (const float*)d_in[6];
    const int*   rel_index  = (const int*)d_in[7];

    f16*   Wqt   = (f16*)d_ws;                          // 768*256*2  = 393216 B
    f16*   Wpt   = (f16*)((char*)d_ws + 393216);        // 256*256*2  = 131072 B
    float* biasp = (float*)((char*)d_ws + 524288);      // 8*64*64*4  = 131072 B

    prep_kernel<<<288, 256, 0, stream>>>(W_qkv, W_proj, bias_table, rel_index, Wqt, Wpt, biasp);
    swin_kernel<<<BWIN, 512, 0, stream>>>(x, var, b_qkv, b_proj, Wqt, Wpt, biasp, (float*)d_out);
}

// Round 2
// 1156.510 us; speedup vs baseline: 1.2262x; 1.2090x over previous
//
#include <hip/hip_runtime.h>

#define NTOK 64
#define DIM 256
#define NH 8
#define BWIN 4096
#define TOPK 51

typedef _Float16 f16;
typedef _Float16 f16x8 __attribute__((ext_vector_type(8)));
typedef _Float16 f16x4 __attribute__((ext_vector_type(4)));
typedef float f32x4 __attribute__((ext_vector_type(4)));

#define MFMA32(a, b, c) __builtin_amdgcn_mfma_f32_16x16x32_f16((a), (b), (c), 0, 0, 0)
#define MFMA16(a, b, c) __builtin_amdgcn_mfma_f32_16x16x16f16((a), (b), (c), 0, 0, 0)

// ---------------- prep: transpose weights to fp16; bias table into MFMA C-fragment layout ----------------
__global__ void prep_kernel(const float* __restrict__ Wqkv, const float* __restrict__ Wproj,
                            const float* __restrict__ bias_table, const int* __restrict__ rel_index,
                            f16* __restrict__ Wqt, f16* __restrict__ Wpt, float* __restrict__ biasp) {
    int tid = blockIdx.x * blockDim.x + threadIdx.x;
    const int nq = 768 * 256, np = 256 * 256, nb = NH * NTOK * NTOK;
    for (int i = tid; i < nq + np + nb; i += gridDim.x * blockDim.x) {
        if (i < nq) {
            int o = i >> 8, d = i & 255;
            Wqt[i] = (f16)Wqkv[d * 768 + o];
        } else if (i < nq + np) {
            int j = i - nq;
            int o = j >> 8, d = j & 255;
            Wpt[j] = (f16)Wproj[d * 256 + o];
        } else {
            int j = i - nq - np;
            int h = j >> 12;          // j / 4096
            int nm = j & 4095;        // n(query)*64 + m(key)
            int n = nm >> 6, m = nm & 63;
            // fragment layout for the swapped-S (K·Q^T) dots:
            //   st[rj][r] at lane(lq*16+lc) = bias[key m=rj*16+lq*4+r][query n=ci*16+lc]
            int ci = n >> 4, lc = n & 15;
            int rj = m >> 4, lq = (m >> 2) & 3, r = m & 3;
            int lane = lq * 16 + lc;
            biasp[((((h * 4 + ci) * 4 + rj) << 6) + lane) * 4 + r] =
                bias_table[rel_index[nm] * NH + h];
        }
    }
}

// ---------------- fused per-window kernel: 1 block (512 thr, 8 waves) per window ----------------
// Wave w handles head h=w end-to-end; dots->softmax->PV fused per query-tile to fit 128 VGPRs.
__global__ __launch_bounds__(512, 4)
void swin_kernel(const float* __restrict__ x, const float* __restrict__ var,
                 const float* __restrict__ b_qkv, const float* __restrict__ b_proj,
                 const f16* __restrict__ Wqt, const f16* __restrict__ Wpt,
                 const float* __restrict__ biasp, float* __restrict__ out) {
    __shared__ __align__(16) struct {
        f16 xv[64][264];                    // var(hi) in phase 1, x in phase 2   33792 B
        union {
            f16 oh[NH][64][40];             // per-head attn output              40960 B
            f16 lo[64][264];                // var low part (phase 1)            33792 B
            float vs[64][65];               // var_self scores                   16640 B
        } u;
        unsigned char mod4[4][4][64][4];    // topk flag, fragment layout         4096 B
    } sm;                                   // total 78848 B -> 2 blocks/CU

    const int tid = threadIdx.x;
    const int lane = tid & 63;
    const int w = tid >> 6;                 // wave 0..7 (= head id in phase 2)
    const int lc = lane & 15;
    const int lq = lane >> 4;
    const int bwin = blockIdx.x;

    const float* varp = var + (size_t)bwin * NTOK * DIM;
    const float* xp = x + (size_t)bwin * NTOK * DIM;
    float* outp = out + (size_t)bwin * NTOK * DIM;

    // ---- phase 0: issue all global loads early; split var into fp16 hi + lo ----
    float4 v4[8], x4[8];
    #pragma unroll
    for (int it = 0; it < 8; ++it) v4[it] = ((const float4*)varp)[it * 512 + tid];
    #pragma unroll
    for (int it = 0; it < 8; ++it) x4[it] = ((const float4*)xp)[it * 512 + tid];
    #pragma unroll
    for (int it = 0; it < 8; ++it) {
        int i = it * 512 + tid;
        int r = i >> 6, c4 = i & 63;
        float4 vv = v4[it];
        f16 h0 = (f16)vv.x, h1 = (f16)vv.y, h2 = (f16)vv.z, h3 = (f16)vv.w;
        f16x4 hv = {h0, h1, h2, h3};
        f16x4 lv = {(f16)(vv.x - (float)h0), (f16)(vv.y - (float)h1),
                    (f16)(vv.z - (float)h2), (f16)(vv.w - (float)h3)};
        *(f16x4*)&sm.xv[r][c4 * 4] = hv;
        *(f16x4*)&sm.u.lo[r][c4 * 4] = lv;
    }
    __syncthreads();

    // ---- phase 1: var_self = var @ var^T (split-fp16, ~fp32 accuracy), 2 tiles/wave ----
    {
        const int rs = w >> 1;
        f32x4 vacc[2];
        vacc[0] = (f32x4){0.f, 0.f, 0.f, 0.f};
        vacc[1] = (f32x4){0.f, 0.f, 0.f, 0.f};
        #pragma unroll
        for (int ks = 0; ks < 8; ++ks) {
            int k0 = ks * 32 + lq * 8;
            f16x8 ahi = *(const f16x8*)&sm.xv[rs * 16 + lc][k0];
            f16x8 alo = *(const f16x8*)&sm.u.lo[rs * 16 + lc][k0];
            #pragma unroll
            for (int m = 0; m < 2; ++m) {
                int mt = (w & 1) * 2 + m;
                f16x8 bhi = *(const f16x8*)&sm.xv[mt * 16 + lc][k0];
                f16x8 blo = *(const f16x8*)&sm.u.lo[mt * 16 + lc][k0];
                vacc[m] = MFMA32(ahi, bhi, vacc[m]);
                vacc[m] = MFMA32(ahi, blo, vacc[m]);
                vacc[m] = MFMA32(alo, bhi, vacc[m]);
            }
        }
        __syncthreads();   // all lo/var-hi reads done before vs (aliased) written / xv overwritten
        #pragma unroll
        for (int m = 0; m < 2; ++m) {
            int mt = (w & 1) * 2 + m;
            #pragma unroll
            for (int r = 0; r < 4; ++r)
                sm.u.vs[rs * 16 + lq * 4 + r][mt * 16 + lc] = vacc[m][r];
        }
    }
    // store x (fp16) into xv (var-hi dead)
    #pragma unroll
    for (int it = 0; it < 8; ++it) {
        int i = it * 512 + tid;
        int r = i >> 6, c4 = i & 63;
        float4 vv = x4[it];
        f16x4 hv = {(f16)vv.x, (f16)vv.y, (f16)vv.z, (f16)vv.w};
        *(f16x4*)&sm.xv[r][c4 * 4] = hv;
    }
    __syncthreads();

    // ---- topk rank count: thread (row=tid>>3, part=tid&7) handles 8 cols; store fragment layout ----
    {
        int n = tid >> 3, part = tid & 7;
        float vm[8];
        int cnt[8];
        #pragma unroll
        for (int i = 0; i < 8; ++i) { vm[i] = sm.u.vs[n][part * 8 + i]; cnt[i] = 0; }
        for (int j = 0; j < 64; ++j) {
            float vj = sm.u.vs[n][j];
            #pragma unroll
            for (int i = 0; i < 8; ++i) {
                int mi = part * 8 + i;
                cnt[i] += (int)((vj > vm[i]) | ((vj == vm[i]) & (j < mi)));
            }
        }
        int ci = n >> 4, lcq = n & 15;
        #pragma unroll
        for (int i = 0; i < 8; ++i) {
            int mi = part * 8 + i;            // key index
            int rj = mi >> 4, lqk = (mi >> 2) & 3, r = mi & 3;
            sm.mod4[ci][rj][lqk * 16 + lcq][r] = (cnt[i] < TOPK) ? 1 : 0;
        }
    }
    __syncthreads();

    // ================= phase 2: wave w == head h, fully register-resident =================
    const int h = w;
    const float scale = 0.17677669529663687f;   // 32^-0.5
    const f16* Wq = Wqt + (size_t)(h * 32) * 256;
    const f16* Wk = Wqt + (size_t)(256 + h * 32) * 256;
    const f16* Wv = Wqt + (size_t)(512 + h * 32) * 256;

    // q^T = Wq·x^T, k^T = Wk·x^T (C-layout == transposed-operand frag), v = x·Wv^T
    f16x4 qop[2][4], kop[2][4], vop[2][4];   // [ot][token-tile] / [d-tile][token-tile]
    {
        f32x4 acc[2][4];
        // ---- q ----
        #pragma unroll
        for (int a = 0; a < 2; ++a)
            #pragma unroll
            for (int b = 0; b < 4; ++b) acc[a][b] = (f32x4){0.f, 0.f, 0.f, 0.f};
        #pragma unroll
        for (int ks = 0; ks < 8; ++ks) {
            int k0 = ks * 32 + lq * 8;
            f16x8 xf[4], wf[2];
            #pragma unroll
            for (int tt = 0; tt < 4; ++tt) xf[tt] = *(const f16x8*)&sm.xv[tt * 16 + lc][k0];
            #pragma unroll
            for (int ot = 0; ot < 2; ++ot) wf[ot] = *(const f16x8*)&Wq[(size_t)(ot * 16 + lc) * 256 + k0];
            #pragma unroll
            for (int ot = 0; ot < 2; ++ot)
                #pragma unroll
                for (int tt = 0; tt < 4; ++tt)
                    acc[ot][tt] = MFMA32(wf[ot], xf[tt], acc[ot][tt]);   // D[outdim][token]
        }
        #pragma unroll
        for (int ot = 0; ot < 2; ++ot) {
            #pragma unroll
            for (int r = 0; r < 4; ++r) {
                float bq = b_qkv[h * 32 + ot * 16 + lq * 4 + r];
                #pragma unroll
                for (int tt = 0; tt < 4; ++tt)
                    qop[ot][tt][r] = (f16)((acc[ot][tt][r] + bq) * scale);
            }
        }
        // ---- k ----
        #pragma unroll
        for (int a = 0; a < 2; ++a)
            #pragma unroll
            for (int b = 0; b < 4; ++b) acc[a][b] = (f32x4){0.f, 0.f, 0.f, 0.f};
        #pragma unroll
        for (int ks = 0; ks < 8; ++ks) {
            int k0 = ks * 32 + lq * 8;
            f16x8 xf[4], wf[2];
            #pragma unroll
            for (int tt = 0; tt < 4; ++tt) xf[tt] = *(const f16x8*)&sm.xv[tt * 16 + lc][k0];
            #pragma unroll
            for (int ot = 0; ot < 2; ++ot) wf[ot] = *(const f16x8*)&Wk[(size_t)(ot * 16 + lc) * 256 + k0];
            #pragma unroll
            for (int ot = 0; ot < 2; ++ot)
                #pragma unroll
                for (int tt = 0; tt < 4; ++tt)
                    acc[ot][tt] = MFMA32(wf[ot], xf[tt], acc[ot][tt]);
        }
        #pragma unroll
        for (int ot = 0; ot < 2; ++ot) {
            #pragma unroll
            for (int r = 0; r < 4; ++r) {
                float bk = b_qkv[256 + h * 32 + ot * 16 + lq * 4 + r];
                #pragma unroll
                for (int tt = 0; tt < 4; ++tt)
                    kop[ot][tt][r] = (f16)(acc[ot][tt][r] + bk);
            }
        }
        // ---- v (untransposed: D[token][d] -> operand is V^T) ----
        #pragma unroll
        for (int a = 0; a < 2; ++a)
            #pragma unroll
            for (int b = 0; b < 4; ++b) acc[a][b] = (f32x4){0.f, 0.f, 0.f, 0.f};
        #pragma unroll
        for (int ks = 0; ks < 8; ++ks) {
            int k0 = ks * 32 + lq * 8;
            f16x8 xf[4], wf[2];
            #pragma unroll
            for (int tt = 0; tt < 4; ++tt) xf[tt] = *(const f16x8*)&sm.xv[tt * 16 + lc][k0];
            #pragma unroll
            for (int cd = 0; cd < 2; ++cd) wf[cd] = *(const f16x8*)&Wv[(size_t)(cd * 16 + lc) * 256 + k0];
            #pragma unroll
            for (int cd = 0; cd < 2; ++cd)
                #pragma unroll
                for (int tt = 0; tt < 4; ++tt)
                    acc[cd][tt] = MFMA32(xf[tt], wf[cd], acc[cd][tt]);   // D[token][d]
        }
        #pragma unroll
        for (int cd = 0; cd < 2; ++cd) {
            float bv = b_qkv[512 + h * 32 + cd * 16 + lc];
            #pragma unroll
            for (int tt = 0; tt < 4; ++tt)
                #pragma unroll
                for (int r = 0; r < 4; ++r)
                    vop[cd][tt][r] = (f16)(acc[cd][tt][r] + bv);
        }
    }

    // ---- fused per-query-tile: dots (S^T = K·Q^T) -> softmax -> PV, all in-register ----
    #pragma unroll
    for (int ci = 0; ci < 4; ++ci) {
        f32x4 st[4];   // S^T tiles: row=key (quad), col=query (lane)
        #pragma unroll
        for (int rj = 0; rj < 4; ++rj) {
            f32x4 z = (f32x4){0.f, 0.f, 0.f, 0.f};
            z = MFMA16(kop[0][rj], qop[0][ci], z);
            st[rj] = MFMA16(kop[1][rj], qop[1][ci], z);
        }
        // bias (fragment-layout, one f32x4 per rj) + topk modifier (one dword per rj)
        float mx = -1e30f;
        #pragma unroll
        for (int rj = 0; rj < 4; ++rj) {
            f32x4 bfr = *(const f32x4*)&biasp[((((h * 4 + ci) * 4 + rj) << 6) + lane) * 4];
            unsigned mbits = *(const unsigned*)&sm.mod4[ci][rj][lane][0];
            #pragma unroll
            for (int r = 0; r < 4; ++r) {
                float modv = ((mbits >> (8 * r)) & 1) ? 1.0f : 1.2f;
                float t = st[rj][r] * modv + bfr[r];
                st[rj][r] = t;
                mx = fmaxf(mx, t);
            }
        }
        mx = fmaxf(mx, __shfl_xor(mx, 16));   // reduce over key rows = quads
        mx = fmaxf(mx, __shfl_xor(mx, 32));
        float s = 0.f;
        #pragma unroll
        for (int rj = 0; rj < 4; ++rj)
            #pragma unroll
            for (int r = 0; r < 4; ++r) {
                float e = __expf(st[rj][r] - mx);
                st[rj][r] = e;
                s += e;
            }
        s += __shfl_xor(s, 16);
        s += __shfl_xor(s, 32);
        // P fragments for this query tile only (8 VGPRs)
        f16x4 pc[4];
        #pragma unroll
        for (int rj = 0; rj < 4; ++rj)
            #pragma unroll
            for (int r = 0; r < 4; ++r)
                pc[rj][r] = (f16)st[rj][r];
        // PV for this tile
        f32x4 oacc[2];
        oacc[0] = (f32x4){0.f, 0.f, 0.f, 0.f};
        oacc[1] = (f32x4){0.f, 0.f, 0.f, 0.f};
        #pragma unroll
        for (int kc = 0; kc < 4; ++kc)
            #pragma unroll
            for (int cd = 0; cd < 2; ++cd)
                oacc[cd] = MFMA16(pc[kc], vop[cd][kc], oacc[cd]);   // D[token][d]
        float inv = 1.0f / s;
        #pragma unroll
        for (int r = 0; r < 4; ++r) {
            float rl = __shfl(inv, lq * 4 + r);   // lsum lives at lane (query&15)
            #pragma unroll
            for (int cd = 0; cd < 2; ++cd)
                sm.u.oh[w][ci * 16 + lq * 4 + r][cd * 16 + lc] = (f16)(oacc[cd][r] * rl);
        }
    }
    __syncthreads();

    // ---- proj: final = concat(oh) @ Wproj + b_proj ; wave owns 32-col strip ----
    {
        f32x4 facc[4][2];
        #pragma unroll
        for (int rt = 0; rt < 4; ++rt)
            #pragma unroll
            for (int ct = 0; ct < 2; ++ct) facc[rt][ct] = (f32x4){0.f, 0.f, 0.f, 0.f};
        #pragma unroll
        for (int hh = 0; hh < NH; ++hh) {
            f16x8 pf[4], wfp[2];
            #pragma unroll
            for (int rt = 0; rt < 4; ++rt)
                pf[rt] = *(const f16x8*)&sm.u.oh[hh][rt * 16 + lc][lq * 8];
            #pragma unroll
            for (int ct = 0; ct < 2; ++ct)
                wfp[ct] = *(const f16x8*)&Wpt[(size_t)(w * 32 + ct * 16 + lc) * 256 + hh * 32 + lq * 8];
            #pragma unroll
            for (int rt = 0; rt < 4; ++rt)
                #pragma unroll
                for (int ct = 0; ct < 2; ++ct)
                    facc[rt][ct] = MFMA32(pf[rt], wfp[ct], facc[rt][ct]);   // D[token][outcol]
        }
        #pragma unroll
        for (int ct = 0; ct < 2; ++ct) {
            int col = w * 32 + ct * 16 + lc;
            float bp = b_proj[col];
            #pragma unroll
            for (int rt = 0; rt < 4; ++rt)
                #pragma unroll
                for (int r = 0; r < 4; ++r)
                    outp[(rt * 16 + lq * 4 + r) * 256 + col] = facc[rt][ct][r] + bp;
        }
    }
}

extern "C" void kernel_launch(void* const* d_in, const int* in_sizes, int n_in,
                              void* d_out, int out_size, void* d_ws, size_t ws_size,
                              hipStream_t stream) {
    const float* x          = (const float*)d_in[0];
    const float* var        = (const float*)d_in[1];
    const float* W_qkv      = (const float*)d_in[2];
    const float* b_qkv      = (const float*)d_in[3];
    const float* W_proj     = (const float*)d_in[4];
    const float* b_proj     = (const float*)d_in[5];
    const float* bias_table = (const float*)d_in[6];
    const int*   rel_index  = (const int*)d_in[7];

    f16*   Wqt   = (f16*)d_ws;                          // 768*256*2  = 393216 B
    f16*   Wpt   = (f16*)((char*)d_ws + 393216);        // 256*256*2  = 131072 B
    float* biasp = (float*)((char*)d_ws + 524288);      // 8*4*4*64*4*4 = 131072 B
    prep_kernel<<<288, 256, 0, stream>>>(W_qkv, W_proj, bias_table, rel_index, Wqt, Wpt, biasp);
    swin_kernel<<<BWIN, 512, 0, stream>>>(x, var, b_qkv, b_proj, Wqt, Wpt, biasp, (float*)d_out);
}